// Round 7
// baseline (245.951 us; speedup 1.0000x reference)
//
#include <hip/hip_runtime.h>
#include <hip/hip_bf16.h>
#include <cstdint>

// Problem constants (match reference)
#define B_SZ     256
#define D_DIM    2048
#define N_PROXY  16384
#define P_POS    4
#define K_SEL    54        // BG_KNN + P
#define TEMP_INV 20.0f     // 1/0.05

typedef __bf16 bf16_t;
typedef __bf16 bf16x4 __attribute__((ext_vector_type(4)));
typedef __bf16 bf16x8 __attribute__((ext_vector_type(8)));
typedef float  f32x4  __attribute__((ext_vector_type(4)));

// global_load_lds, width 16: per-lane global source address; LDS dest =
// WAVE-UNIFORM base + lane*16 (hardware-applied).  No destination VGPR ->
// no compiler auto-waitcnt; ordering is our explicit counted s_waitcnt.
__device__ __forceinline__ void gload_lds16(const void* g, void* l) {
    __builtin_amdgcn_global_load_lds(
        (const __attribute__((address_space(1))) void*)g,
        (__attribute__((address_space(3))) void*)l, 16, 0, 0);
}

// ---------------------------------------------------------------------------
// Kernel 0: F fp32 [256,2048] -> Fb bf16 in MFMA-A fragment-major layout.
// frag slot g = (mb*64 + kt)*64 + lane holds A[m=mb*16+(lane&15)]
// [k = kt*32 + (lane>>4)*8 + j], j=0..7.  Also zeroes the loss accumulator.
// ---------------------------------------------------------------------------
__global__ __launch_bounds__(256)
void conv_feat(const float* __restrict__ F, bf16_t* __restrict__ Fb,
               float* __restrict__ out) {
    int g    = blockIdx.x * 256 + threadIdx.x;   // 0..65535
    if (g == 0) *out = 0.0f;
    int lane = g & 63;
    int kt   = (g >> 6) & 63;
    int mb   = g >> 12;                          // 0..15
    int frow = lane & 15;
    int quad = (lane >> 4) & 3;
    const float* src = F + (size_t)(mb * 16 + frow) * D_DIM + kt * 32 + quad * 8;
    float4 lo = *(const float4*)src;
    float4 hi = *(const float4*)(src + 4);
    bf16x8 o = { (bf16_t)lo.x, (bf16_t)lo.y, (bf16_t)lo.z, (bf16_t)lo.w,
                 (bf16_t)hi.x, (bf16_t)hi.y, (bf16_t)hi.z, (bf16_t)hi.w };
    *(bf16x8*)(Fb + (size_t)g * 8) = o;
}

// ---------------------------------------------------------------------------
// Kernel 1: Sb = bf16((F @ em.T)/TEMP).  BM=256, BN=64, BK=32, grid 256,
// 512 threads (8 waves; wave w computes rows w*32..w*32+31, all 64 cols).
//
// v7b (= v7 + prologue hardening; v7 hit an infra failure, never measured):
// - v6 (zero reg-dest loads) fixed the wait-chain serialization
//   (77.5 -> ~61 us) but was LDS-read-bound: fp32 B tiles doubled read
//   bytes and the 128-B row stride cost ~8-way bank conflicts
//   (SQ_LDS_BANK_CONFLICT 4.19M).
// - B returns to the PROVEN bf16 frag-major LDS layout (contiguous 1 KB
//   frags, near-zero read conflicts in r1), cvt on the WRITE side; B is
//   reg-staged via a NAMED depth-4 float4 ring (issue k+3, consume k+1).
// - A stays on the v6 global_load_lds 4-ring (reg-dest A at depth 1 was
//   the r0-r3 poison).
// - Per-step VMEM = 3 ops/wave {B-reg, A-gld, A-gld}, each step's ops are
//   confined between "memory"-clobber barriers => at step K's
//   s_waitcnt vmcnt(6), the newest 6 ops are exactly steps K and K-1, so
//   tile K+1 is provably landed while K+2/K+3 stay in flight.
// - HARDENING vs v7: the prologue now issues per-tile windows
//   {B,A,A}|{B,A,A}|{B,A,A} separated by compiler memory barriers.  v7
//   issued B0,B1,B2 then 6 A-glds in ONE window, so worst-case compiler
//   scheduling left A-tile-1 among the 6 newest at step 0's vmcnt(6) —
//   an off-by-one race on the first K-step.  Now every wait has the same
//   window structure as steady state.
// Fragment VALUES identical to the verified kernels -> absmax stays 0.
// ---------------------------------------------------------------------------
__global__ __launch_bounds__(512)
void gemm_score(const bf16_t* __restrict__ Fb, const float* __restrict__ E,
                bf16_t* __restrict__ Sb) {
    const int tid  = threadIdx.x;
    const int bn   = blockIdx.x;          // 64-col n-stripe
    const int lane = tid & 63;
    const int w    = tid >> 6;            // wave 0..7
    const int frow = lane & 15;
    const int quad = (lane >> 4) & 3;

    // A ring: 4 tiles x 16 KB (frag-major bf16, staged by global_load_lds).
    // B: double-buffered bf16 frag-major tile (frag n = 1 KB at n*1024 B,
    // lane-slot l' = frow+16*quad at l'*16 B).  72 KB total.
    __shared__ __attribute__((aligned(16))) char   Als[4][16384];
    __shared__ __attribute__((aligned(16))) bf16_t Bls[2][2048];

    // ---- A staging (per wave): frags mb = 2w, 2w+1.
    // Frag (mb,kt) is 1 KB contiguous at byte (mb*64+kt)*1024 + lane*16.
    const char* aS0 = (const char*)Fb + ((w * 2 + 0) * 64) * 1024 + lane * 16;
    const char* aS1 = (const char*)Fb + ((w * 2 + 1) * 64) * 1024 + lane * 16;
    const int   aD0 = (w * 2 + 0) * 1024;       // wave-uniform LDS dests
    const int   aD1 = (w * 2 + 1) * 1024;
    const int   aR0 = aD0 + lane * 16;          // read addrs
    const int   aR1 = aD1 + lane * 16;

    // ---- B reg staging (per thread): row r = tid>>3, fp32 col c4.
    const int r  = tid >> 3;              // 0..63
    const int c4 = (tid & 7) * 4;
    const float* bsrc = E + (size_t)(bn * 64 + r) * D_DIM + c4;
    // frag-major dest (bf16 units): n*512 + (fr+16*qd)*8 + half*4
    const int bdst = (r >> 4) * 512 + ((r & 15) + 16 * (c4 >> 3)) * 8
                   + ((c4 >> 2) & 1) * 4;

    f32x4 c00 = {}, c01 = {}, c02 = {}, c03 = {};
    f32x4 c10 = {}, c11 = {}, c12 = {}, c13 = {};

    // Named B ring: tile t lives in q[t&3].
    float4 q0, q1, q2, q3;

    // ---- prologue: per-tile issue windows, each closed by a compiler
    // memory barrier so the counted waits see the same 3-op window
    // structure as the steady-state loop.
    float4 t0 = *(const float4*)(bsrc);                 // B tile 0
    gload_lds16(aS0 + 0 * 1024, &Als[0][0] + aD0);      // A tile 0
    gload_lds16(aS1 + 0 * 1024, &Als[0][0] + aD1);
    asm volatile("" ::: "memory");
    q1 = *(const float4*)(bsrc + 32);                   // B tile 1
    gload_lds16(aS0 + 1 * 1024, &Als[1][0] + aD0);      // A tile 1
    gload_lds16(aS1 + 1 * 1024, &Als[1][0] + aD1);
    asm volatile("" ::: "memory");
    q2 = *(const float4*)(bsrc + 64);                   // B tile 2
    gload_lds16(aS0 + 2 * 1024, &Als[2][0] + aD0);      // A tile 2
    gload_lds16(aS1 + 2 * 1024, &Als[2][0] + aD1);
    asm volatile("" ::: "memory");
    q0 = t0; q3 = t0;                     // silence uninit; overwritten in loop
    {
        bf16x4 h = { (bf16_t)t0.x, (bf16_t)t0.y, (bf16_t)t0.z, (bf16_t)t0.w };
        *(bf16x4*)(&Bls[0][0] + bdst) = h;
    }
    // newest 6 VMEM ops = windows {tile1, tile2} => tile 0 (A) landed.
    asm volatile("s_waitcnt vmcnt(6)" ::: "memory");
    asm volatile("s_waitcnt lgkmcnt(0)" ::: "memory");
    __builtin_amdgcn_s_barrier();
    asm volatile("" ::: "memory");

    // STEP(K): issue B tile K+3 -> QI, A tile K+3 -> Als[(K+3)&3];
    // ds_read A/B tile K (contiguous b128); 8 MFMA; cvt QC (tile K+1)
    // -> Bls[(K+1)&1]; vmcnt(6) [newest 6 = steps K,K-1 => tile K+1's
    // A-gloads landed]; lgkmcnt(0); barrier.
#define STEP(K, QI, QC)                                                        \
    {                                                                          \
        QI = *(const float4*)(bsrc + (size_t)(((K) + 3) & 63) * 32);           \
        {                                                                      \
            const int tt_ = ((K) + 3) & 63;                                    \
            char* d_ = &Als[((K) + 3) & 3][0];                                 \
            gload_lds16(aS0 + tt_ * 1024, d_ + aD0);                           \
            gload_lds16(aS1 + tt_ * 1024, d_ + aD1);                           \
        }                                                                      \
        const char*   sa_ = &Als[(K) & 3][0];                                  \
        const bf16_t* sb_ = &Bls[(K) & 1][0];                                  \
        bf16x8 af0 = *(const bf16x8*)(sa_ + aR0);                              \
        bf16x8 af1 = *(const bf16x8*)(sa_ + aR1);                              \
        bf16x8 bg0 = *(const bf16x8*)(sb_ + 0 * 512 + lane * 8);               \
        bf16x8 bg1 = *(const bf16x8*)(sb_ + 1 * 512 + lane * 8);               \
        bf16x8 bg2 = *(const bf16x8*)(sb_ + 2 * 512 + lane * 8);               \
        bf16x8 bg3 = *(const bf16x8*)(sb_ + 3 * 512 + lane * 8);               \
        c00 = __builtin_amdgcn_mfma_f32_16x16x32_bf16(af0, bg0, c00, 0, 0, 0); \
        c01 = __builtin_amdgcn_mfma_f32_16x16x32_bf16(af0, bg1, c01, 0, 0, 0); \
        c02 = __builtin_amdgcn_mfma_f32_16x16x32_bf16(af0, bg2, c02, 0, 0, 0); \
        c03 = __builtin_amdgcn_mfma_f32_16x16x32_bf16(af0, bg3, c03, 0, 0, 0); \
        c10 = __builtin_amdgcn_mfma_f32_16x16x32_bf16(af1, bg0, c10, 0, 0, 0); \
        c11 = __builtin_amdgcn_mfma_f32_16x16x32_bf16(af1, bg1, c11, 0, 0, 0); \
        c12 = __builtin_amdgcn_mfma_f32_16x16x32_bf16(af1, bg2, c12, 0, 0, 0); \
        c13 = __builtin_amdgcn_mfma_f32_16x16x32_bf16(af1, bg3, c13, 0, 0, 0); \
        {                                                                      \
            bf16x4 h_ = { (bf16_t)QC.x, (bf16_t)QC.y,                          \
                          (bf16_t)QC.z, (bf16_t)QC.w };                        \
            *(bf16x4*)(&Bls[((K) + 1) & 1][0] + bdst) = h_;                    \
        }                                                                      \
        asm volatile("s_waitcnt vmcnt(6)" ::: "memory");                       \
        asm volatile("s_waitcnt lgkmcnt(0)" ::: "memory");                     \
        __builtin_amdgcn_s_barrier();                                          \
        asm volatile("" ::: "memory");                                         \
    }

    // Period-4 name rotation: tile t -> q[t&3]; QI = q[(k+3)&3], QC = q[(k+1)&3].
    for (int k0 = 0; k0 < 64; k0 += 4) {
        STEP(k0 + 0, q3, q1)
        STEP(k0 + 1, q0, q2)
        STEP(k0 + 2, q1, q3)
        STEP(k0 + 3, q2, q0)
    }
#undef STEP

    // ---- epilogue: C/D layout col=lane&15, row=quad*4+i; fold 1/TEMP ----
    {
        int gr0 = w * 32 + quad * 4;            // m=0 row base
        int gr1 = gr0 + 16;                     // m=1 row base
#define CWRITE(CV, GR, N)                                                      \
        {                                                                      \
            int gc = bn * 64 + (N) * 16 + frow;                                \
            _Pragma("unroll")                                                  \
            for (int i = 0; i < 4; ++i)                                        \
                Sb[(size_t)((GR) + i) * N_PROXY + gc] =                        \
                    (bf16_t)(CV[i] * TEMP_INV);                                \
        }
        CWRITE(c00, gr0, 0) CWRITE(c01, gr0, 1) CWRITE(c02, gr0, 2) CWRITE(c03, gr0, 3)
        CWRITE(c10, gr1, 0) CWRITE(c11, gr1, 1) CWRITE(c12, gr1, 2) CWRITE(c13, gr1, 3)
#undef CWRITE
    }
}

// ---------------------------------------------------------------------------
// Kernel 2: per-row top-K + log-softmax loss on bf16 scores.
// 512 threads/row, 32 keys/thread; 16-bit radix select with early exit.
// (unchanged this round — one structural change at a time)
// ---------------------------------------------------------------------------
__device__ __forceinline__ float key16_to_float(uint32_t k) {
    uint32_t bits16 = (k & 0x8000u) ? (k ^ 0x8000u) : ((~k) & 0xFFFFu);
    return __uint_as_float(bits16 << 16);
}

__device__ __forceinline__ int block_sum_i(int v, int tid, volatile int* rbuf) {
#pragma unroll
    for (int o = 32; o > 0; o >>= 1) v += __shfl_down(v, o, 64);
    __syncthreads();
    if ((tid & 63) == 0) rbuf[tid >> 6] = v;
    __syncthreads();
    int s = 0;
#pragma unroll
    for (int w = 0; w < 8; ++w) s += rbuf[w];
    return s;
}

__device__ __forceinline__ float block_sum_f(float v, int tid, volatile float* rbuf) {
#pragma unroll
    for (int o = 32; o > 0; o >>= 1) v += __shfl_down(v, o, 64);
    __syncthreads();
    if ((tid & 63) == 0) rbuf[tid >> 6] = v;
    __syncthreads();
    float s = 0.0f;
#pragma unroll
    for (int w = 0; w < 8; ++w) s += rbuf[w];
    return s;
}

__device__ __forceinline__ uint32_t block_max_u(uint32_t v, int tid,
                                                volatile uint32_t* rbuf) {
#pragma unroll
    for (int o = 32; o > 0; o >>= 1) {
        uint32_t w = __shfl_down(v, o, 64);
        v = (w > v) ? w : v;
    }
    __syncthreads();
    if ((tid & 63) == 0) rbuf[tid >> 6] = v;
    __syncthreads();
    uint32_t r = 0;
#pragma unroll
    for (int w = 0; w < 8; ++w) r = rbuf[w] > r ? rbuf[w] : r;
    return r;
}

__global__ __launch_bounds__(512)
void topk_loss(const bf16_t* __restrict__ S, const int* __restrict__ targets,
               const int* __restrict__ plabel, const int* __restrict__ ptable,
               float* __restrict__ out) {
    const int b    = blockIdx.x;
    const int tid  = threadIdx.x;
    const int lane = tid & 63;
    const int wave = tid >> 6;

    __shared__ int      sh_pos[4];
    __shared__ float    sh_pv[4];
    __shared__ int      sh_d;
    __shared__ int      rbuf_i[8];
    __shared__ float    rbuf_f[8];
    __shared__ uint32_t rbuf_u[8];
    __shared__ uint32_t cand_ls[64];
    __shared__ int      candcnt;
    __shared__ float    sh_numbg;

    const bf16_t* row = S + (size_t)b * N_PROXY;

    if (tid == 0) {
        int t  = targets[b];
        int py = plabel[t];
        int pos[4]; int d = 0;
        for (int j = 0; j < 4; ++j) {
            int p = ptable[py * 4 + j];
            bool dup = false;
            for (int i = 0; i < d; ++i) dup = dup || (pos[i] == p);
            if (!dup) pos[d++] = p;
        }
        sh_d = d;
        for (int j = 0; j < 4; ++j) sh_pos[j] = (j < d) ? pos[j] : -1;
        for (int j = 0; j < 4; ++j) sh_pv[j]  = (j < d) ? (float)row[pos[j]] : 0.0f;
        candcnt = 0;
    }
    __syncthreads();

    const int d  = sh_d;
    const int p0 = sh_pos[0], p1 = sh_pos[1], p2 = sh_pos[2], p3 = sh_pos[3];
    float pv[4];
#pragma unroll
    for (int j = 0; j < 4; ++j) pv[j] = sh_pv[j];

    // ---- 32 bf16 logits/thread as 16-bit sortable keys; positives -> 0 ----
    uint32_t keys[32];
#pragma unroll
    for (int j = 0; j < 4; ++j) {
        int g8 = j * 512 + tid;                     // 8-element granule
        ushort v[8];
        *(uint4*)v = *(const uint4*)(row + (size_t)g8 * 8);
#pragma unroll
        for (int q = 0; q < 8; ++q) {
            int idx = g8 * 8 + q;
            bool isp = (idx == p0) | (idx == p1) | (idx == p2) | (idx == p3);
            uint32_t bits = v[q];
            uint32_t key  = (bits & 0x8000u) ? ((~bits) & 0xFFFFu)
                                             : (bits | 0x8000u);
            keys[j * 8 + q] = isp ? 0u : key;
        }
    }

    const int need = K_SEL - d;              // backgrounds in the top-54 set

    // ---- 16-bit radix select with early exit ----
    uint32_t T = 0;
    for (int bit = 15; bit >= 0; --bit) {
        uint32_t cnd = T | (1u << bit);
        int c = 0;
#pragma unroll
        for (int j = 0; j < 32; ++j) c += (keys[j] >= cnd) ? 1 : 0;
        int ct = block_sum_i(c, tid, rbuf_i);
        if (ct >= need) {
            T = cnd;
            if (ct == need) break;           // selected set is exactly top-need
        }
    }
    const float vT = key16_to_float(T);

    // ---- stability max over backgrounds + positives ----
    uint32_t kmax = 0;
#pragma unroll
    for (int j = 0; j < 32; ++j) kmax = keys[j] > kmax ? keys[j] : kmax;
    kmax = block_max_u(kmax, tid, rbuf_u);
    float mx = key16_to_float(kmax);
    for (int j = 0; j < 4; ++j) if (j < d && pv[j] > mx) mx = pv[j];

    // ---- lse over selected set: strict-greater + exact tie fill + pos ----
    int c1 = 0; float se = 0.0f;
#pragma unroll
    for (int j = 0; j < 32; ++j) {
        if (keys[j] > T) { c1 += 1; se += __expf(key16_to_float(keys[j]) - mx); }
    }
    int   c1t = block_sum_i(c1, tid, rbuf_i);
    float set = block_sum_f(se, tid, rbuf_f);
    set += (float)(need - c1t) * __expf(vT - mx);
    for (int j = 0; j < 4; ++j) if (j < d) set += __expf(pv[j] - mx);
    const float lse = mx + logf(set);

    // ---- numerator: distinct positives + top (P-d) background values ----
    float num = 0.0f;
    for (int j = 0; j < 4; ++j) if (j < d) num += pv[j];
    if (d < P_POS) {
#pragma unroll
        for (int j = 0; j < 32; ++j) {
            if (keys[j] > T) {
                int p = atomicAdd(&candcnt, 1);
                cand_ls[p] = keys[j];
            }
        }
        __syncthreads();
        if (wave == 0) {
            const int cc = candcnt;
            uint32_t v = (lane < cc) ? cand_ls[lane] : T;   // pad with T (exact)
            float s = 0.0f;
            const int need2 = P_POS - d;                    // 1..3
            for (int it = 0; it < need2; ++it) {
                uint32_t m = v;
#pragma unroll
                for (int o = 32; o > 0; o >>= 1) {
                    uint32_t w = __shfl_xor(m, o, 64);
                    m = (w > m) ? w : m;
                }
                s += key16_to_float(m);
                unsigned long long msk = __ballot(v == m);
                int first = __ffsll(msk) - 1;
                if (lane == first) v = 0u;
            }
            if (lane == 0) sh_numbg = s;
        }
        __syncthreads();
        num += sh_numbg;
    }

    const float loss_b = lse - num * (1.0f / P_POS);
    if (tid == 0) atomicAdd(out, loss_b * (1.0f / B_SZ));
}

// ---------------------------------------------------------------------------
extern "C" void kernel_launch(void* const* d_in, const int* in_sizes, int n_in,
                              void* d_out, int out_size, void* d_ws, size_t ws_size,
                              hipStream_t stream) {
    const float* F       = (const float*)d_in[0];   // features [256,2048]
    const float* E       = (const float*)d_in[1];   // global_memory [16384,2048]
    const int*   targets = (const int*)d_in[2];     // [256]
    const int*   plabel  = (const int*)d_in[3];     // [32768]
    const int*   ptable  = (const int*)d_in[4];     // [4096,4]

    bf16_t* Fb = (bf16_t*)d_ws;                                     // 1 MB, frag-major
    bf16_t* Sb = (bf16_t*)((char*)d_ws + (size_t)B_SZ * D_DIM * 2); // 8 MB
    float*  out = (float*)d_out;

    // out is zeroed by conv_feat (stream-ordered before topk_loss's atomics)
    hipLaunchKernelGGL(conv_feat, dim3(256), dim3(256), 0, stream, F, Fb, out);
    hipLaunchKernelGGL(gemm_score, dim3(N_PROXY / 64), dim3(512), 0, stream,
                       Fb, E, Sb);
    hipLaunchKernelGGL(topk_loss, dim3(B_SZ), dim3(512), 0, stream,
                       Sb, targets, plabel, ptable, out);
}

// Round 8
// 233.581 us; speedup vs baseline: 1.0530x; 1.0530x over previous
//
#include <hip/hip_runtime.h>
#include <hip/hip_bf16.h>
#include <cstdint>

// Problem constants (match reference)
#define B_SZ     256
#define D_DIM    2048
#define N_PROXY  16384
#define P_POS    4
#define K_SEL    54        // BG_KNN + P
#define TEMP_INV 20.0f     // 1/0.05

typedef __bf16 bf16_t;
typedef __bf16 bf16x4 __attribute__((ext_vector_type(4)));
typedef __bf16 bf16x8 __attribute__((ext_vector_type(8)));
typedef float  f32x4  __attribute__((ext_vector_type(4)));

// global_load_lds, width 16: per-lane global source address; LDS dest =
// WAVE-UNIFORM base + lane*16 (hardware-applied).  No destination VGPR ->
// no compiler auto-waitcnt; ordering is our explicit counted s_waitcnt.
__device__ __forceinline__ void gload_lds16(const void* g, void* l) {
    __builtin_amdgcn_global_load_lds(
        (const __attribute__((address_space(1))) void*)g,
        (__attribute__((address_space(3))) void*)l, 16, 0, 0);
}

// ---------------------------------------------------------------------------
// Kernel 0: F fp32 [256,2048] -> Fb bf16 in MFMA-A fragment-major layout.
// frag slot g = (mb*64 + kt)*64 + lane holds A[m=mb*16+(lane&15)]
// [k = kt*32 + (lane>>4)*8 + j], j=0..7.  Also zeroes the loss accumulator.
// ---------------------------------------------------------------------------
__global__ __launch_bounds__(256)
void conv_feat(const float* __restrict__ F, bf16_t* __restrict__ Fb,
               float* __restrict__ out) {
    int g    = blockIdx.x * 256 + threadIdx.x;   // 0..65535
    if (g == 0) *out = 0.0f;
    int lane = g & 63;
    int kt   = (g >> 6) & 63;
    int mb   = g >> 12;                          // 0..15
    int frow = lane & 15;
    int quad = (lane >> 4) & 3;
    const float* src = F + (size_t)(mb * 16 + frow) * D_DIM + kt * 32 + quad * 8;
    float4 lo = *(const float4*)src;
    float4 hi = *(const float4*)(src + 4);
    bf16x8 o = { (bf16_t)lo.x, (bf16_t)lo.y, (bf16_t)lo.z, (bf16_t)lo.w,
                 (bf16_t)hi.x, (bf16_t)hi.y, (bf16_t)hi.z, (bf16_t)hi.w };
    *(bf16x8*)(Fb + (size_t)g * 8) = o;
}

// ---------------------------------------------------------------------------
// Kernel 1: Sb = bf16((F @ em.T)/TEMP).  BM=256, BN=64, BK=32, grid 256,
// 512 threads (8 waves).
//
// v8 = v6 (the 61-us best) + rebalanced wave tiles + prologue hardening.
// EMPIRICAL LAW (6 data points, r0-r7): any register-destination global
// load in the K-loop => ~75 us (the compiler's conservative vmcnt(0) after
// opaque asm drains the queue every step); zero reg-dest loads (v6) =>
// 61 us.  So: both operands stay on global_load_lds 4-deep rings with one
// counted s_waitcnt vmcnt(6) per step (3 ops/wave/step: {A,A,B}); tile
// K+1 provably landed, K+2/K+3 in flight.
//
// v8 change: wave tile 32x64 -> 64x32 (wm=w>>1, wn=w&1).  Per wave per
// step: 4 A frags (4 KB) + 2 B frags (4 KB fp32) = 8 KB vs v6's 10 KB ->
// per-CU LDS reads 80 -> 64 KB/step (LDS is the dominant shared resource);
// ds_reads 10 -> 8 per wave; same 8 MFMAs; STAGING BYTE-IDENTICAL to v6.
// Prologue staged as per-tile windows with compiler memory barriers (v7b
// hardening; v6 had a latent off-by-one at the prologue seam).
// B granule-XOR (slot gx holds global granule gx^(row&7), applied on the
// per-lane GLOBAL source; re-applied on the read address) keeps B reads at
// the b128 bank floor.  fp32->bf16 cvt on the read side (VALU, overlaps).
// Fragment VALUES identical to the verified kernels -> absmax stays 0.
// ---------------------------------------------------------------------------
__global__ __launch_bounds__(512)
void gemm_score(const bf16_t* __restrict__ Fb, const float* __restrict__ E,
                bf16_t* __restrict__ Sb) {
    const int tid  = threadIdx.x;
    const int bn   = blockIdx.x;          // 64-col n-stripe
    const int lane = tid & 63;
    const int w    = tid >> 6;            // wave 0..7
    const int frow = lane & 15;
    const int quad = (lane >> 4) & 3;
    const int wm   = w >> 1;              // row-block 0..3 (64 rows each)
    const int wn   = w & 1;               // col-block 0..1 (32 cols each)

    // Ring of 4 tile buffers; each: A [16 frags][64 lanes][16B] = 16 KB,
    // then B [64 rows][8 grans][16B] = 8 KB.  96 KB total.  (= v6 layout)
    __shared__ __attribute__((aligned(16))) char tile[4][24576];

    // ---- staging sources (per-lane, BYTE-IDENTICAL to v6) ----
    // A: wave w stages frags mb = 2w, 2w+1 (staging assignment is
    // independent of the read assignment; all 16 frags covered).
    const char* aS0 = (const char*)Fb + ((w * 2 + 0) * 64) * 1024 + lane * 16;
    const char* aS1 = (const char*)Fb + ((w * 2 + 1) * 64) * 1024 + lane * 16;
    // B: wave w stages rows w*8..w*8+7; LDS slot (row,gx) holds global
    // granule gx^(row&7); row&7 == lane>>3 -> src granule (lane&7)^(lane>>3).
    const char* bS = (const char*)E
                   + (size_t)(bn * 64 + w * 8 + (lane >> 3)) * (D_DIM * 4)
                   + (((lane & 7) ^ (lane >> 3)) * 16);

    // ---- staging LDS dests (wave-uniform; HW adds lane*16) ----
    const int aD0 = (w * 2 + 0) * 1024;
    const int aD1 = (w * 2 + 1) * 1024;
    const int bD  = 16384 + w * 1024;

    // ---- read-side constants (v8 mapping) ----
    // A frags wm*4+m, m=0..3:
    const int aR = (wm * 4) * 1024 + lane * 16;            // +m*1024
    // B frags f = wn*2+{0,1}: row f*16+frow at byte f*2048+frow*128;
    // granules (2q)^(frow&7) and ^1:
    const int x0 = (((quad << 1)) ^ (frow & 7)) << 4;
    const int x1 = x0 ^ 16;
    const int bR = 16384 + (wn * 2) * 2048 + frow * 128;   // +n*2048

    // Accumulators: c[m][n], m=0..3 (16-row blocks), n=0..1 (16-col blocks)
    f32x4 c00 = {}, c01 = {};
    f32x4 c10 = {}, c11 = {};
    f32x4 c20 = {}, c21 = {};
    f32x4 c30 = {}, c31 = {};

    // ---- prologue: per-tile issue windows {A,A,B} | {A,A,B} | {A,A,B},
    // each closed by a compiler memory barrier => every counted wait sees
    // the same 3-op window structure as the steady-state loop.
    gload_lds16(aS0 + 0 * 1024, &tile[0][0] + aD0);
    gload_lds16(aS1 + 0 * 1024, &tile[0][0] + aD1);
    gload_lds16(bS  + 0 * 128,  &tile[0][0] + bD);
    asm volatile("" ::: "memory");
    gload_lds16(aS0 + 1 * 1024, &tile[1][0] + aD0);
    gload_lds16(aS1 + 1 * 1024, &tile[1][0] + aD1);
    gload_lds16(bS  + 1 * 128,  &tile[1][0] + bD);
    asm volatile("" ::: "memory");
    gload_lds16(aS0 + 2 * 1024, &tile[2][0] + aD0);
    gload_lds16(aS1 + 2 * 1024, &tile[2][0] + aD1);
    gload_lds16(bS  + 2 * 128,  &tile[2][0] + bD);
    asm volatile("" ::: "memory");
    // newest 6 = tiles 1,2 => tile 0 landed.
    asm volatile("s_waitcnt vmcnt(6)" ::: "memory");
    __builtin_amdgcn_s_barrier();
    asm volatile("" ::: "memory");

    // STEP(K): issue tile K+3 {A,A,B}; ds_read tile K (4 A b128 + 4 B b128);
    // cvt; 8 MFMA; vmcnt(6) [newest 6 = steps K,K-1 => tile K+1 landed];
    // lgkmcnt(0); barrier.
#define STEP(K)                                                                \
    {                                                                          \
        {                                                                      \
            const int tt_ = ((K) + 3) & 63;                                    \
            char* d_ = &tile[((K) + 3) & 3][0];                                \
            gload_lds16(aS0 + tt_ * 1024, d_ + aD0);                           \
            gload_lds16(aS1 + tt_ * 1024, d_ + aD1);                           \
            gload_lds16(bS  + (size_t)tt_ * 128, d_ + bD);                     \
        }                                                                      \
        const char* s_ = &tile[(K) & 3][0];                                    \
        bf16x8 af0 = *(const bf16x8*)(s_ + aR + 0 * 1024);                     \
        bf16x8 af1 = *(const bf16x8*)(s_ + aR + 1 * 1024);                     \
        bf16x8 af2 = *(const bf16x8*)(s_ + aR + 2 * 1024);                     \
        bf16x8 af3 = *(const bf16x8*)(s_ + aR + 3 * 1024);                     \
        f32x4 l0 = *(const f32x4*)(s_ + bR + 0 * 2048 + x0);                   \
        f32x4 h0 = *(const f32x4*)(s_ + bR + 0 * 2048 + x1);                   \
        f32x4 l1 = *(const f32x4*)(s_ + bR + 1 * 2048 + x0);                   \
        f32x4 h1 = *(const f32x4*)(s_ + bR + 1 * 2048 + x1);                   \
        bf16x8 bg0 = { (bf16_t)l0[0], (bf16_t)l0[1], (bf16_t)l0[2],            \
                       (bf16_t)l0[3], (bf16_t)h0[0], (bf16_t)h0[1],            \
                       (bf16_t)h0[2], (bf16_t)h0[3] };                         \
        bf16x8 bg1 = { (bf16_t)l1[0], (bf16_t)l1[1], (bf16_t)l1[2],            \
                       (bf16_t)l1[3], (bf16_t)h1[0], (bf16_t)h1[1],            \
                       (bf16_t)h1[2], (bf16_t)h1[3] };                         \
        c00 = __builtin_amdgcn_mfma_f32_16x16x32_bf16(af0, bg0, c00, 0, 0, 0); \
        c01 = __builtin_amdgcn_mfma_f32_16x16x32_bf16(af0, bg1, c01, 0, 0, 0); \
        c10 = __builtin_amdgcn_mfma_f32_16x16x32_bf16(af1, bg0, c10, 0, 0, 0); \
        c11 = __builtin_amdgcn_mfma_f32_16x16x32_bf16(af1, bg1, c11, 0, 0, 0); \
        c20 = __builtin_amdgcn_mfma_f32_16x16x32_bf16(af2, bg0, c20, 0, 0, 0); \
        c21 = __builtin_amdgcn_mfma_f32_16x16x32_bf16(af2, bg1, c21, 0, 0, 0); \
        c30 = __builtin_amdgcn_mfma_f32_16x16x32_bf16(af3, bg0, c30, 0, 0, 0); \
        c31 = __builtin_amdgcn_mfma_f32_16x16x32_bf16(af3, bg1, c31, 0, 0, 0); \
        asm volatile("s_waitcnt vmcnt(6)" ::: "memory");                       \
        asm volatile("s_waitcnt lgkmcnt(0)" ::: "memory");                     \
        __builtin_amdgcn_s_barrier();                                          \
        asm volatile("" ::: "memory");                                         \
    }

    for (int k = 0; k < 64; k += 4) {
        STEP(k + 0)
        STEP(k + 1)
        STEP(k + 2)
        STEP(k + 3)
    }
#undef STEP

    // ---- epilogue: C/D layout col=lane&15, row=quad*4+i; fold 1/TEMP ----
    // rows: wm*64 + m*16 + quad*4 + i; cols: bn*64 + wn*32 + n*16 + frow.
    {
        const int grb = wm * 64 + quad * 4;
        const int gcb = bn * 64 + wn * 32 + frow;
#define CWRITE(CV, M, N)                                                       \
        {                                                                      \
            int gr = grb + (M) * 16;                                           \
            int gc = gcb + (N) * 16;                                           \
            _Pragma("unroll")                                                  \
            for (int i = 0; i < 4; ++i)                                        \
                Sb[(size_t)(gr + i) * N_PROXY + gc] =                          \
                    (bf16_t)(CV[i] * TEMP_INV);                                \
        }
        CWRITE(c00, 0, 0) CWRITE(c01, 0, 1)
        CWRITE(c10, 1, 0) CWRITE(c11, 1, 1)
        CWRITE(c20, 2, 0) CWRITE(c21, 2, 1)
        CWRITE(c30, 3, 0) CWRITE(c31, 3, 1)
#undef CWRITE
    }
}

// ---------------------------------------------------------------------------
// Kernel 2: per-row top-K + log-softmax loss on bf16 scores.
// 512 threads/row, 32 keys/thread; 16-bit radix select with early exit.
// (unchanged this round — one structural change at a time)
// ---------------------------------------------------------------------------
__device__ __forceinline__ float key16_to_float(uint32_t k) {
    uint32_t bits16 = (k & 0x8000u) ? (k ^ 0x8000u) : ((~k) & 0xFFFFu);
    return __uint_as_float(bits16 << 16);
}

__device__ __forceinline__ int block_sum_i(int v, int tid, volatile int* rbuf) {
#pragma unroll
    for (int o = 32; o > 0; o >>= 1) v += __shfl_down(v, o, 64);
    __syncthreads();
    if ((tid & 63) == 0) rbuf[tid >> 6] = v;
    __syncthreads();
    int s = 0;
#pragma unroll
    for (int w = 0; w < 8; ++w) s += rbuf[w];
    return s;
}

__device__ __forceinline__ float block_sum_f(float v, int tid, volatile float* rbuf) {
#pragma unroll
    for (int o = 32; o > 0; o >>= 1) v += __shfl_down(v, o, 64);
    __syncthreads();
    if ((tid & 63) == 0) rbuf[tid >> 6] = v;
    __syncthreads();
    float s = 0.0f;
#pragma unroll
    for (int w = 0; w < 8; ++w) s += rbuf[w];
    return s;
}

__device__ __forceinline__ uint32_t block_max_u(uint32_t v, int tid,
                                                volatile uint32_t* rbuf) {
#pragma unroll
    for (int o = 32; o > 0; o >>= 1) {
        uint32_t w = __shfl_down(v, o, 64);
        v = (w > v) ? w : v;
    }
    __syncthreads();
    if ((tid & 63) == 0) rbuf[tid >> 6] = v;
    __syncthreads();
    uint32_t r = 0;
#pragma unroll
    for (int w = 0; w < 8; ++w) r = rbuf[w] > r ? rbuf[w] : r;
    return r;
}

__global__ __launch_bounds__(512)
void topk_loss(const bf16_t* __restrict__ S, const int* __restrict__ targets,
               const int* __restrict__ plabel, const int* __restrict__ ptable,
               float* __restrict__ out) {
    const int b    = blockIdx.x;
    const int tid  = threadIdx.x;
    const int lane = tid & 63;
    const int wave = tid >> 6;

    __shared__ int      sh_pos[4];
    __shared__ float    sh_pv[4];
    __shared__ int      sh_d;
    __shared__ int      rbuf_i[8];
    __shared__ float    rbuf_f[8];
    __shared__ uint32_t rbuf_u[8];
    __shared__ uint32_t cand_ls[64];
    __shared__ int      candcnt;
    __shared__ float    sh_numbg;

    const bf16_t* row = S + (size_t)b * N_PROXY;

    if (tid == 0) {
        int t  = targets[b];
        int py = plabel[t];
        int pos[4]; int d = 0;
        for (int j = 0; j < 4; ++j) {
            int p = ptable[py * 4 + j];
            bool dup = false;
            for (int i = 0; i < d; ++i) dup = dup || (pos[i] == p);
            if (!dup) pos[d++] = p;
        }
        sh_d = d;
        for (int j = 0; j < 4; ++j) sh_pos[j] = (j < d) ? pos[j] : -1;
        for (int j = 0; j < 4; ++j) sh_pv[j]  = (j < d) ? (float)row[pos[j]] : 0.0f;
        candcnt = 0;
    }
    __syncthreads();

    const int d  = sh_d;
    const int p0 = sh_pos[0], p1 = sh_pos[1], p2 = sh_pos[2], p3 = sh_pos[3];
    float pv[4];
#pragma unroll
    for (int j = 0; j < 4; ++j) pv[j] = sh_pv[j];

    // ---- 32 bf16 logits/thread as 16-bit sortable keys; positives -> 0 ----
    uint32_t keys[32];
#pragma unroll
    for (int j = 0; j < 4; ++j) {
        int g8 = j * 512 + tid;                     // 8-element granule
        ushort v[8];
        *(uint4*)v = *(const uint4*)(row + (size_t)g8 * 8);
#pragma unroll
        for (int q = 0; q < 8; ++q) {
            int idx = g8 * 8 + q;
            bool isp = (idx == p0) | (idx == p1) | (idx == p2) | (idx == p3);
            uint32_t bits = v[q];
            uint32_t key  = (bits & 0x8000u) ? ((~bits) & 0xFFFFu)
                                             : (bits | 0x8000u);
            keys[j * 8 + q] = isp ? 0u : key;
        }
    }

    const int need = K_SEL - d;              // backgrounds in the top-54 set

    // ---- 16-bit radix select with early exit ----
    uint32_t T = 0;
    for (int bit = 15; bit >= 0; --bit) {
        uint32_t cnd = T | (1u << bit);
        int c = 0;
#pragma unroll
        for (int j = 0; j < 32; ++j) c += (keys[j] >= cnd) ? 1 : 0;
        int ct = block_sum_i(c, tid, rbuf_i);
        if (ct >= need) {
            T = cnd;
            if (ct == need) break;           // selected set is exactly top-need
        }
    }
    const float vT = key16_to_float(T);

    // ---- stability max over backgrounds + positives ----
    uint32_t kmax = 0;
#pragma unroll
    for (int j = 0; j < 32; ++j) kmax = keys[j] > kmax ? keys[j] : kmax;
    kmax = block_max_u(kmax, tid, rbuf_u);
    float mx = key16_to_float(kmax);
    for (int j = 0; j < 4; ++j) if (j < d && pv[j] > mx) mx = pv[j];

    // ---- lse over selected set: strict-greater + exact tie fill + pos ----
    int c1 = 0; float se = 0.0f;
#pragma unroll
    for (int j = 0; j < 32; ++j) {
        if (keys[j] > T) { c1 += 1; se += __expf(key16_to_float(keys[j]) - mx); }
    }
    int   c1t = block_sum_i(c1, tid, rbuf_i);
    float set = block_sum_f(se, tid, rbuf_f);
    set += (float)(need - c1t) * __expf(vT - mx);
    for (int j = 0; j < 4; ++j) if (j < d) set += __expf(pv[j] - mx);
    const float lse = mx + logf(set);

    // ---- numerator: distinct positives + top (P-d) background values ----
    float num = 0.0f;
    for (int j = 0; j < 4; ++j) if (j < d) num += pv[j];
    if (d < P_POS) {
#pragma unroll
        for (int j = 0; j < 32; ++j) {
            if (keys[j] > T) {
                int p = atomicAdd(&candcnt, 1);
                cand_ls[p] = keys[j];
            }
        }
        __syncthreads();
        if (wave == 0) {
            const int cc = candcnt;
            uint32_t v = (lane < cc) ? cand_ls[lane] : T;   // pad with T (exact)
            float s = 0.0f;
            const int need2 = P_POS - d;                    // 1..3
            for (int it = 0; it < need2; ++it) {
                uint32_t m = v;
#pragma unroll
                for (int o = 32; o > 0; o >>= 1) {
                    uint32_t w = __shfl_xor(m, o, 64);
                    m = (w > m) ? w : m;
                }
                s += key16_to_float(m);
                unsigned long long msk = __ballot(v == m);
                int first = __ffsll(msk) - 1;
                if (lane == first) v = 0u;
            }
            if (lane == 0) sh_numbg = s;
        }
        __syncthreads();
        num += sh_numbg;
    }

    const float loss_b = lse - num * (1.0f / P_POS);
    if (tid == 0) atomicAdd(out, loss_b * (1.0f / B_SZ));
}

// ---------------------------------------------------------------------------
extern "C" void kernel_launch(void* const* d_in, const int* in_sizes, int n_in,
                              void* d_out, int out_size, void* d_ws, size_t ws_size,
                              hipStream_t stream) {
    const float* F       = (const float*)d_in[0];   // features [256,2048]
    const float* E       = (const float*)d_in[1];   // global_memory [16384,2048]
    const int*   targets = (const int*)d_in[2];     // [256]
    const int*   plabel  = (const int*)d_in[3];     // [32768]
    const int*   ptable  = (const int*)d_in[4];     // [4096,4]

    bf16_t* Fb = (bf16_t*)d_ws;                                     // 1 MB, frag-major
    bf16_t* Sb = (bf16_t*)((char*)d_ws + (size_t)B_SZ * D_DIM * 2); // 8 MB
    float*  out = (float*)d_out;

    // out is zeroed by conv_feat (stream-ordered before topk_loss's atomics)
    hipLaunchKernelGGL(conv_feat, dim3(256), dim3(256), 0, stream, F, Fb, out);
    hipLaunchKernelGGL(gemm_score, dim3(N_PROXY / 64), dim3(512), 0, stream,
                       Fb, E, Sb);
    hipLaunchKernelGGL(topk_loss, dim3(B_SZ), dim3(512), 0, stream,
                       Sb, targets, plabel, ptable, out);
}